// Round 8
// baseline (4896.624 us; speedup 1.0000x reference)
//
#include <hip/hip_runtime.h>
#include <hip/hip_bf16.h>
#include <stdint.h>

#define B_ 8
#define S_ 512
#define H_ 1024
#define V_ 32000
#define D_ 768
#define G3H (3*H_)

typedef __bf16 bf16x8_t __attribute__((ext_vector_type(8)));
typedef float f32x4_t __attribute__((ext_vector_type(4)));

__device__ __forceinline__ unsigned short f2bf(float f) {
  unsigned int u = __float_as_uint(f);
  u += 0x7fffu + ((u >> 16) & 1u);      // RNE
  return (unsigned short)(u >> 16);
}
__device__ __forceinline__ float fast_sigmoid(float x) {
  float e = __builtin_amdgcn_exp2f(x * -1.44269504088896340736f);
  return __builtin_amdgcn_rcpf(1.0f + e);
}
__device__ __forceinline__ float fast_tanh(float x) {
  float e = __builtin_amdgcn_exp2f(x * -2.88539008177792681472f);
  return 2.0f * __builtin_amdgcn_rcpf(1.0f + e) - 1.0f;
}

// ---------------- small prep kernels ----------------
__global__ void zero_buf(uint4* __restrict__ p, int n) {
  int i = blockIdx.x * 256 + threadIdx.x;
  if (i < n) p[i] = uint4{0, 0, 0, 0};
}

__global__ void ctx_mean(const float* __restrict__ c, float* __restrict__ ctx) {
  int b = blockIdx.x;
  for (int d = threadIdx.x; d < D_; d += 256) {
    float s = 0.f;
    #pragma unroll
    for (int n = 0; n < 16; ++n) s += c[((size_t)b * 16 + n) * D_ + d];
    ctx[b * D_ + d] = s * (1.0f / 16.0f);
  }
}

// fp32 h0 for register h_prev AND tagged 8B chunks (tag 0) into slot 0 of each
// layer's h buffer. Chunk = [vals:u32 (2 bf16)][tag:u32].
// hb0: 4 slots x 8192 u32; hb1: 2 slots x 8192 u32.
__global__ void h0_compute(const float* __restrict__ ctx, const float* __restrict__ w,
                           const float* __restrict__ bias, float* __restrict__ h0l,
                           uint32_t* __restrict__ hb0, uint32_t* __restrict__ hb1) {
  int o = blockIdx.x * 256 + threadIdx.x;   // 8192 unit-pairs
  int layer = o >> 12, b = (o >> 9) & 7, p = o & 511;
  int row = layer * 1024 + 2 * p;
  float s0 = bias[row], s1 = bias[row + 1];
  const float* cb = ctx + b * D_;
  const float* w0 = w + (size_t)row * D_;
  const float* w1 = w0 + D_;
  for (int d = 0; d < D_; ++d) { s0 += cb[d] * w0[d]; s1 += cb[d] * w1[d]; }
  h0l[layer * 8192 + b * 1024 + 2 * p] = s0;
  h0l[layer * 8192 + b * 1024 + 2 * p + 1] = s1;
  uint32_t vals = ((uint32_t)f2bf(s1) << 16) | (uint32_t)f2bf(s0);
  uint32_t* dst = (layer ? hb1 : hb0) + ((size_t)b * 512 + p) * 2;
  dst[0] = vals;
  dst[1] = 0u;   // tag 0
}

__global__ void gather_embed(const int* __restrict__ seq, const float* __restrict__ emb,
                             unsigned short* __restrict__ x) {
  int r = blockIdx.x;                       // 0..4095 = b*512+s
  int idx = seq[r];
  float4 v = ((const float4*)(emb + (size_t)idx * H_))[threadIdx.x];
  ushort4 o;
  o.x = f2bf(v.x); o.y = f2bf(v.y); o.z = f2bf(v.z); o.w = f2bf(v.w);
  ((ushort4*)(x + (size_t)r * H_))[threadIdx.x] = o;
}

__global__ void f32_to_bf16(const float* __restrict__ in, unsigned short* __restrict__ outp, long n4) {
  long i = blockIdx.x * (long)blockDim.x + threadIdx.x;
  long stride = (long)gridDim.x * blockDim.x;
  for (; i < n4; i += stride) {
    float4 v = ((const float4*)in)[i];
    ushort4 o;
    o.x = f2bf(v.x); o.y = f2bf(v.y); o.z = f2bf(v.z); o.w = f2bf(v.w);
    ((ushort4*)outp)[i] = o;
  }
}

// ---------------- bf16 MFMA GEMM: C[M,N] = A[M,K] * B[N,K]^T + bias[N] ----------------
__global__ __launch_bounds__(256) void gemm_bt_bf16(
    const unsigned short* __restrict__ A, const unsigned short* __restrict__ B,
    float* __restrict__ C, const float* __restrict__ bias,
    int M, int N, int K)
{
  __shared__ __align__(16) unsigned short As[128 * 32];
  __shared__ __align__(16) unsigned short Bs[128 * 32];
  const int tid = threadIdx.x;
  const int l = tid & 63;
  const int w = tid >> 6;
  const int wr = w >> 1, wc = w & 1;
  const long row0 = (long)blockIdx.y * 128;
  const long col0 = (long)blockIdx.x * 128;

  f32x4_t acc[4][4];
  #pragma unroll
  for (int m = 0; m < 4; ++m)
    #pragma unroll
    for (int n = 0; n < 4; ++n) acc[m][n] = (f32x4_t)0.0f;

  const int sr = tid >> 2;
  const int sc = (tid & 3) << 3;

  for (int kt = 0; kt < K; kt += 32) {
    __syncthreads();
    uint4 a0 = *(const uint4*)&A[(row0 + sr) * K + kt + sc];
    uint4 a1 = *(const uint4*)&A[(row0 + sr + 64) * K + kt + sc];
    uint4 b0 = *(const uint4*)&B[(col0 + sr) * K + kt + sc];
    uint4 b1 = *(const uint4*)&B[(col0 + sr + 64) * K + kt + sc];
    ((uint4*)As)[tid]       = a0;
    ((uint4*)As)[tid + 256] = a1;
    ((uint4*)Bs)[tid]       = b0;
    ((uint4*)Bs)[tid + 256] = b1;
    __syncthreads();

    bf16x8_t af[4], bfr[4];
    #pragma unroll
    for (int m = 0; m < 4; ++m)
      af[m] = *(const bf16x8_t*)&As[(wr * 64 + m * 16 + (l & 15)) * 32 + (l >> 4) * 8];
    #pragma unroll
    for (int n = 0; n < 4; ++n)
      bfr[n] = *(const bf16x8_t*)&Bs[(wc * 64 + n * 16 + (l & 15)) * 32 + (l >> 4) * 8];
    #pragma unroll
    for (int m = 0; m < 4; ++m)
      #pragma unroll
      for (int n = 0; n < 4; ++n)
        acc[m][n] = __builtin_amdgcn_mfma_f32_16x16x32_bf16(af[m], bfr[n], acc[m][n], 0, 0, 0);
  }

  #pragma unroll
  for (int n = 0; n < 4; ++n) {
    const long col = col0 + wc * 64 + n * 16 + (l & 15);
    const float bv = bias[col];
    #pragma unroll
    for (int m = 0; m < 4; ++m) {
      const long rbase = row0 + wr * 64 + m * 16 + ((l >> 4) << 2);
      #pragma unroll
      for (int v = 0; v < 4; ++v)
        C[(rbase + v) * (long)N + col] = acc[m][n][v] + bv;
    }
  }
}

// ---------------- fused 2-layer persistent GRU, tagged-chunk sync ----------------
// 256 blocks x 256 threads. layer = blk>>7, units j0=(blk&127)*8 (24 W-rows, 2 tiles).
// h traffic = 8B chunks [2 bf16 | tag]: store IS the release; validated load IS
// the acquire. One flag array only for L1->L0 WAR back-pressure (3-epoch slack).
__device__ __forceinline__ void load_wfrag(const float* __restrict__ W, int j0, int w,
                                           int l15, int lhi, bf16x8_t wf[2][8]) {
  #pragma unroll
  for (int m = 0; m < 2; ++m) {
    const int idx = m * 16 + l15;           // row within the 24
    const int gg = idx >> 3, uu = idx & 7;
    #pragma unroll
    for (int c = 0; c < 8; ++c) {
      f32x4_t v0 = {0.f, 0.f, 0.f, 0.f}, v1 = {0.f, 0.f, 0.f, 0.f};
      if (idx < 24) {
        const float* p = W + (size_t)((gg << 10) + j0 + uu) * 1024
                           + (w << 8) + (c << 5) + (lhi << 3);
        v0 = *(const f32x4_t*)p;
        v1 = *(const f32x4_t*)(p + 4);
      }
      bf16x8_t f;
      f[0] = (__bf16)v0[0]; f[1] = (__bf16)v0[1]; f[2] = (__bf16)v0[2]; f[3] = (__bf16)v0[3];
      f[4] = (__bf16)v1[0]; f[5] = (__bf16)v1[1]; f[6] = (__bf16)v1[2]; f[7] = (__bf16)v1[3];
      wf[m][c] = f;
    }
  }
}

__device__ __forceinline__ bf16x8_t pack_frag(const uint4 a, const uint4 b) {
  uint4 r; r.x = a.x; r.y = a.z; r.z = b.x; r.w = b.z;
  return __builtin_bit_cast(bf16x8_t, r);
}

__global__ __launch_bounds__(256, 1) void gru_fused(
    const float* __restrict__ xg,       // [8,512,3072] layer-0 input gates (incl b_ih0)
    const float* __restrict__ w_hh,     // [2,3072,1024]
    const float* __restrict__ w_ih,     // [2,3072,1024]
    const float* __restrict__ b_hh,     // [2,3072]
    const float* __restrict__ b_ih,     // [2,3072]
    const float* __restrict__ h0f,      // [2,8,1024]
    unsigned short* __restrict__ y,     // [8,512,1024] final output bf16
    uint32_t* __restrict__ hb0,         // [4 slots][8][512] 8B tagged chunks
    uint32_t* __restrict__ hb1,         // [2 slots][8][512] 8B tagged chunks
    int* __restrict__ fl)               // [128*32] L1 read-progress flags
{
  __shared__ __align__(16) float red[2 * 4 * 3 * 256];   // 24KB, parity-dbuf
  const int tid = threadIdx.x;
  const int blk = blockIdx.x;
  const int layer = blk >> 7;
  const int j0 = (blk & 127) * 8;
  const int w = tid >> 6;
  const int l = tid & 63;
  const int l15 = l & 15;
  const int lhi = l >> 4;
  const bool realrow = (l15 < 8);

  bf16x8_t wfh[2][8], wfi[2][8];
  #pragma unroll
  for (int m = 0; m < 2; ++m)
    #pragma unroll
    for (int c = 0; c < 8; ++c) wfi[m][c] = (bf16x8_t)(__bf16)0.0f;
  load_wfrag(w_hh + (size_t)layer * G3H * H_, j0, w, l15, lhi, wfh);
  if (layer == 1) load_wfrag(w_ih + (size_t)G3H * H_, j0, w, l15, lhi, wfi);

  // gate-thread state (tid<32): unit pair up=tid&3 (units 2up,2up+1), batch bb=tid>>2
  const int up = tid & 3;
  const int bb = tid >> 2;
  float gbr0 = 0.f, gbz0 = 0.f, gbnh0 = 0.f, gbni0 = 0.f, hp0 = 0.f;
  float gbr1 = 0.f, gbz1 = 0.f, gbnh1 = 0.f, gbni1 = 0.f, hp1 = 0.f;
  const float* xgp = nullptr;
  if (tid < 32) {
    const float* bhh_l = b_hh + (size_t)layer * G3H;
    const float* bih_l = b_ih + (size_t)layer * G3H;
    const int uj = j0 + 2 * up;
    float bhr0 = bhh_l[uj],     bhz0 = bhh_l[1024 + uj],     bhn0 = bhh_l[2048 + uj];
    float bhr1 = bhh_l[uj + 1], bhz1 = bhh_l[1024 + uj + 1], bhn1 = bhh_l[2048 + uj + 1];
    if (layer == 0) {
      gbr0 = bhr0; gbz0 = bhz0; gbnh0 = bhn0;
      gbr1 = bhr1; gbz1 = bhz1; gbnh1 = bhn1;
      xgp = xg + (size_t)(bb * S_) * G3H + uj;
    } else {
      gbr0 = bhr0 + bih_l[uj];     gbz0 = bhz0 + bih_l[1024 + uj];
      gbnh0 = bhn0;                gbni0 = bih_l[2048 + uj];
      gbr1 = bhr1 + bih_l[uj + 1]; gbz1 = bhz1 + bih_l[1024 + uj + 1];
      gbnh1 = bhn1;                gbni1 = bih_l[2048 + uj + 1];
    }
    float2 h2 = *(const float2*)&h0f[(size_t)layer * 8192 + bb * 1024 + uj];
    hp0 = h2.x; hp1 = h2.y;
  }

  // per-lane chunk offset within a slot (u32 units): (row*512 + pair)*2
  const int lane_off = ((l15 << 9) + (w << 7) + (lhi << 2)) * 2;
  const bool fduty = (layer == 0) && (tid >= 64 && tid < 192);
  int* flp = fl + (tid - 64) * 32;

  __syncthreads();

  for (int e = 0; e <= S_; ++e) {
    const bool act = (layer == 0) ? (e < S_) : (e >= 1);
    const int t = (layer == 0) ? e : (e - 1);
    const int p = e & 1;

    f32x4_t a0h = (f32x4_t)0.0f, a1h = (f32x4_t)0.0f, a1i = (f32x4_t)0.0f;
    float2 xr2 = {0.f, 0.f}, xz2 = {0.f, 0.f}, xn2 = {0.f, 0.f};
    int flv = 0x7fffffff;

    if (act) {
      if (layer == 0) {
        // ---- flag ride-along (off critical path; checked after validate) ----
        if (fduty)
          asm volatile("global_load_dword %0, %1, off sc0 sc1"
                       : "=v"(flv) : "v"(flp) : "memory");
        if (tid < 32) {
          const float* xp = xgp + (size_t)t * G3H;
          xr2 = *(const float2*)xp;
          xz2 = *(const float2*)(xp + 1024);
          xn2 = *(const float2*)(xp + 2048);
        }
        const uint32_t* rb = hb0 + (size_t)(e & 3) * 8192 + lane_off;
        const uint32_t tg = (uint32_t)e;
        uint4 q0[8], q1[8];
        #pragma unroll
        for (int c = 0; c < 8; ++c) { q0[c] = uint4{0,0,0,0}; q1[c] = uint4{0,0,0,0}; }
        if (realrow) {
          #pragma unroll
          for (int c = 0; c < 8; ++c)
            asm volatile("global_load_dwordx4 %0, %2, off offset:%3 sc0 sc1\n\t"
                         "global_load_dwordx4 %1, %2, off offset:%4 sc0 sc1"
                         : "=&v"(q0[c]), "=&v"(q1[c])
                         : "v"(rb), "i"(c * 128), "i"(c * 128 + 16) : "memory");
        }
        asm volatile("s_waitcnt vmcnt(0)" ::: "memory");
        __builtin_amdgcn_sched_barrier(0);
        for (;;) {
          uint32_t bad = 0;
          if (realrow) {
            #pragma unroll
            for (int c = 0; c < 8; ++c)
              bad |= (q0[c].y ^ tg) | (q0[c].w ^ tg) | (q1[c].y ^ tg) | (q1[c].w ^ tg);
          }
          if (!__any(bad != 0)) break;
          if (realrow) {
            #pragma unroll
            for (int c = 0; c < 8; ++c)
              asm volatile("global_load_dwordx4 %0, %2, off offset:%3 sc0 sc1\n\t"
                           "global_load_dwordx4 %1, %2, off offset:%4 sc0 sc1"
                           : "=&v"(q0[c]), "=&v"(q1[c])
                           : "v"(rb), "i"(c * 128), "i"(c * 128 + 16) : "memory");
          }
          asm volatile("s_waitcnt vmcnt(0)" ::: "memory");
          __builtin_amdgcn_sched_barrier(0);
        }
        // WAR back-pressure: L1 must be >= e-3 before we overwrite slot (e+1)&3
        if (fduty) {
          while (flv < e - 3) {
            __builtin_amdgcn_s_sleep(1);
            flv = __hip_atomic_load(flp, __ATOMIC_RELAXED, __HIP_MEMORY_SCOPE_AGENT);
          }
        }
        __builtin_amdgcn_sched_barrier(0);
        #pragma unroll
        for (int c = 0; c < 8; ++c) {
          bf16x8_t hf = pack_frag(q0[c], q1[c]);
          a0h = __builtin_amdgcn_mfma_f32_16x16x32_bf16(wfh[0][c], hf, a0h, 0, 0, 0);
          a1h = __builtin_amdgcn_mfma_f32_16x16x32_bf16(wfh[1][c], hf, a1h, 0, 0, 0);
        }
      } else {
        const uint32_t* yb = hb0 + (size_t)(e & 3) * 8192 + lane_off;        // y0_{e-1}, tag e
        const uint32_t* hbm = hb1 + (size_t)((e + 1) & 1) * 8192 + lane_off; // h1 prev, tag e-1
        const uint32_t tgy = (uint32_t)e, tgh = (uint32_t)(e - 1);
        uint4 qy0[8], qy1[8], qh0[8], qh1[8];
        #pragma unroll
        for (int c = 0; c < 8; ++c) {
          qy0[c] = uint4{0,0,0,0}; qy1[c] = uint4{0,0,0,0};
          qh0[c] = uint4{0,0,0,0}; qh1[c] = uint4{0,0,0,0};
        }
        if (realrow) {
          #pragma unroll
          for (int c = 0; c < 8; ++c)
            asm volatile("global_load_dwordx4 %0, %2, off offset:%3 sc0 sc1\n\t"
                         "global_load_dwordx4 %1, %2, off offset:%4 sc0 sc1"
                         : "=&v"(qy0[c]), "=&v"(qy1[c])
                         : "v"(yb), "i"(c * 128), "i"(c * 128 + 16) : "memory");
          #pragma unroll
          for (int c = 0; c < 8; ++c)
            asm volatile("global_load_dwordx4 %0, %2, off offset:%3 sc0 sc1\n\t"
                         "global_load_dwordx4 %1, %2, off offset:%4 sc0 sc1"
                         : "=&v"(qh0[c]), "=&v"(qh1[c])
                         : "v"(hbm), "i"(c * 128), "i"(c * 128 + 16) : "memory");
        }
        asm volatile("s_waitcnt vmcnt(0)" ::: "memory");
        __builtin_amdgcn_sched_barrier(0);
        for (;;) {
          uint32_t bad = 0;
          if (realrow) {
            #pragma unroll
            for (int c = 0; c < 8; ++c) {
              bad |= (qy0[c].y ^ tgy) | (qy0[c].w ^ tgy) | (qy1[c].y ^ tgy) | (qy1[c].w ^ tgy);
              bad |= (qh0[c].y ^ tgh) | (qh0[c].w ^ tgh) | (qh1[c].y ^ tgh) | (qh1[c].w ^ tgh);
            }
          }
          if (!__any(bad != 0)) break;
          if (realrow) {
            #pragma unroll
            for (int c = 0; c < 8; ++c)
              asm volatile("global_load_dwordx4 %0, %2, off offset:%3 sc0 sc1\n\t"
                           "global_load_dwordx4 %1, %2, off offset:%4 sc0 sc1"
                           : "=&v"(qy0[c]), "=&v"(qy1[c])
                           : "v"(yb), "i"(c * 128), "i"(c * 128 + 16) : "memory");
            #pragma unroll
            for (int c = 0; c < 8; ++c)
              asm volatile("global_load_dwordx4 %0, %2, off offset:%3 sc0 sc1\n\t"
                           "global_load_dwordx4 %1, %2, off offset:%4 sc0 sc1"
                           : "=&v"(qh0[c]), "=&v"(qh1[c])
                           : "v"(hbm), "i"(c * 128), "i"(c * 128 + 16) : "memory");
          }
          asm volatile("s_waitcnt vmcnt(0)" ::: "memory");
          __builtin_amdgcn_sched_barrier(0);
        }
        __builtin_amdgcn_sched_barrier(0);
        #pragma unroll
        for (int c = 0; c < 8; ++c) {
          bf16x8_t hf = pack_frag(qh0[c], qh1[c]);
          bf16x8_t yf = pack_frag(qy0[c], qy1[c]);
          a0h = __builtin_amdgcn_mfma_f32_16x16x32_bf16(wfh[0][c], hf, a0h, 0, 0, 0);
          a1h = __builtin_amdgcn_mfma_f32_16x16x32_bf16(wfh[1][c], hf, a1h, 0, 0, 0);
          a0h = __builtin_amdgcn_mfma_f32_16x16x32_bf16(wfi[0][c], yf, a0h, 0, 0, 0);
          a1i = __builtin_amdgcn_mfma_f32_16x16x32_bf16(wfi[1][c], yf, a1i, 0, 0, 0);
        }
      }
      float* rp = red + p * 3072 + (w * 3) * 256 + (l << 2);
      *(f32x4_t*)(rp)       = a0h;
      *(f32x4_t*)(rp + 256) = a1h;
      *(f32x4_t*)(rp + 512) = a1i;
    }
    __syncthreads();   // red[p] ready; reads of this epoch complete block-wide

    // L1 posts read-progress (frees L0 to rotate hb0 slots)
    if (layer == 1 && act && tid == 0)
      __hip_atomic_store(&fl[(blk & 127) * 32], e,
                         __ATOMIC_RELAXED, __HIP_MEMORY_SCOPE_AGENT);

    if (act && tid < 32) {
      const int u0 = 2 * up, u1 = u0 + 1;
      const int i0 = ((((u0 >> 2) << 4) | bb) << 2) + (u0 & 3);
      const int i1 = ((((u1 >> 2) << 4) | bb) << 2) + (u1 & 3);
      const float* rbase = red + p * 3072;
      float aR0 = 0.f, aZ0 = 0.f, aNh0 = 0.f, aNi0 = 0.f;
      float aR1 = 0.f, aZ1 = 0.f, aNh1 = 0.f, aNi1 = 0.f;
      #pragma unroll
      for (int ww = 0; ww < 4; ++ww) {
        const float* rw = rbase + ww * 768;
        aR0  += rw[i0];        aR1  += rw[i1];
        aZ0  += rw[128 + i0];  aZ1  += rw[128 + i1];
        aNh0 += rw[256 + i0];  aNh1 += rw[256 + i1];
        aNi0 += rw[512 + i0];  aNi1 += rw[512 + i1];
      }
      float r0, z0, n0, r1, z1, n1;
      if (layer == 0) {
        r0 = fast_sigmoid(xr2.x + gbr0 + aR0);
        z0 = fast_sigmoid(xz2.x + gbz0 + aZ0);
        n0 = fast_tanh(xn2.x + r0 * (aNh0 + gbnh0));
        r1 = fast_sigmoid(xr2.y + gbr1 + aR1);
        z1 = fast_sigmoid(xz2.y + gbz1 + aZ1);
        n1 = fast_tanh(xn2.y + r1 * (aNh1 + gbnh1));
      } else {
        r0 = fast_sigmoid(aR0 + gbr0);
        z0 = fast_sigmoid(aZ0 + gbz0);
        n0 = fast_tanh(aNi0 + gbni0 + r0 * (aNh0 + gbnh0));
        r1 = fast_sigmoid(aR1 + gbr1);
        z1 = fast_sigmoid(aZ1 + gbz1);
        n1 = fast_tanh(aNi1 + gbni1 + r1 * (aNh1 + gbnh1));
      }
      hp0 = (1.0f - z0) * n0 + z0 * hp0;
      hp1 = (1.0f - z1) * n1 + z1 * hp1;
      uint32_t vals = ((uint32_t)f2bf(hp1) << 16) | (uint32_t)f2bf(hp0);
      const uint32_t wtag = (layer == 0) ? (uint32_t)(e + 1) : (uint32_t)e;
      unsigned long long chunk = ((unsigned long long)wtag << 32) | vals;
      uint32_t* hdst = (layer == 0)
          ? (hb0 + (size_t)((e + 1) & 3) * 8192 + ((size_t)bb * 512 + (j0 >> 1) + up) * 2)
          : (hb1 + (size_t)(e & 1) * 8192 + ((size_t)bb * 512 + (j0 >> 1) + up) * 2);
      if (layer == 1)
        *(uint32_t*)&y[(((size_t)(bb * S_ + t)) << 10) + j0 + 2 * up] = vals;
      asm volatile("global_store_dwordx2 %0, %1, off sc0 sc1"
                   :: "v"(hdst), "v"(chunk) : "memory");
      // no drain, no flag: the tagged store IS the release.
    }
  }
}

// ---------------- launch ----------------
extern "C" void kernel_launch(void* const* d_in, const int* in_sizes, int n_in,
                              void* d_out, int out_size, void* d_ws, size_t ws_size,
                              hipStream_t stream) {
  (void)in_sizes; (void)n_in; (void)out_size; (void)ws_size;
  const float* concepts = (const float*)d_in[0];
  const int*   seq      = (const int*)d_in[1];
  const float* emb      = (const float*)d_in[2];
  const float* w_ih     = (const float*)d_in[3];
  const float* w_hh     = (const float*)d_in[4];
  const float* b_ih     = (const float*)d_in[5];
  const float* b_hh     = (const float*)d_in[6];
  const float* fc_w     = (const float*)d_in[7];
  const float* fc_b     = (const float*)d_in[8];
  const float* c2h_w    = (const float*)d_in[9];
  const float* c2h_b    = (const float*)d_in[10];
  float* out = (float*)d_out;

  char* ws = (char*)d_ws;
  size_t off = 0;
  auto alloc = [&](size_t bytes) {
    char* p = ws + off;
    off += (bytes + 255) & ~(size_t)255;
    return p;
  };
  unsigned short* xy   = (unsigned short*)alloc((size_t)B_ * S_ * H_ * 2);   // x bf16, then y
  float*          xg   = (float*)alloc((size_t)B_ * S_ * G3H * 4);           // layer-0 input gates
  unsigned short* wihb = (unsigned short*)alloc((size_t)G3H * H_ * 2);       // layer-0 W_ih bf16
  unsigned short* fcwb = (unsigned short*)alloc((size_t)V_ * H_ * 2);
  float*          ctx  = (float*)alloc((size_t)B_ * D_ * 4);
  float*          h0l  = (float*)alloc((size_t)2 * B_ * H_ * 4);
  uint32_t*       hb0  = (uint32_t*)alloc((size_t)4 * 8192 * 4);             // 128KB tagged L0
  uint32_t*       hb1  = (uint32_t*)alloc((size_t)2 * 8192 * 4);             // 64KB tagged L1
  int*            fl   = (int*)alloc((size_t)128 * 32 * 4);                  // 16KB flags

  // flags MUST be zeroed every launch (monotone counters)
  zero_buf<<<dim3(4), dim3(256), 0, stream>>>((uint4*)fl, 128 * 32 / 4);
  ctx_mean<<<dim3(8), dim3(256), 0, stream>>>(concepts, ctx);
  h0_compute<<<dim3(32), dim3(256), 0, stream>>>(ctx, c2h_w, c2h_b, h0l, hb0, hb1);
  gather_embed<<<dim3(B_ * S_), dim3(256), 0, stream>>>(seq, emb, xy);
  f32_to_bf16<<<dim3(1024), dim3(256), 0, stream>>>(w_ih, wihb, (long)G3H * H_ / 4);
  f32_to_bf16<<<dim3(2048), dim3(256), 0, stream>>>(fc_w, fcwb, (long)V_ * H_ / 4);

  // layer-0 input gates (GEMM)
  gemm_bt_bf16<<<dim3(G3H / 128, (B_ * S_) / 128), dim3(256), 0, stream>>>(
      xy, wihb, xg, b_ih, B_ * S_, G3H, H_);

  // fused 2-layer skewed recurrence (self-tagged chunk sync)
  gru_fused<<<dim3(256), dim3(256), 0, stream>>>(
      xg, w_hh, w_ih, b_hh, b_ih, h0l, xy, hb0, hb1, fl);

  // logits
  gemm_bt_bf16<<<dim3(V_ / 128, (B_ * S_) / 128), dim3(256), 0, stream>>>(
      xy, fcwb, out, fc_b, B_ * S_, V_, H_);
}

// Round 9
// 4006.739 us; speedup vs baseline: 1.2221x; 1.2221x over previous
//
#include <hip/hip_runtime.h>
#include <hip/hip_bf16.h>
#include <stdint.h>

#define B_ 8
#define S_ 512
#define H_ 1024
#define V_ 32000
#define D_ 768
#define G3H (3*H_)

typedef __bf16 bf16x8_t __attribute__((ext_vector_type(8)));
typedef float f32x4_t __attribute__((ext_vector_type(4)));

__device__ __forceinline__ unsigned short f2bf(float f) {
  unsigned int u = __float_as_uint(f);
  u += 0x7fffu + ((u >> 16) & 1u);      // RNE
  return (unsigned short)(u >> 16);
}
__device__ __forceinline__ float fast_sigmoid(float x) {
  float e = __builtin_amdgcn_exp2f(x * -1.44269504088896340736f);
  return __builtin_amdgcn_rcpf(1.0f + e);
}
__device__ __forceinline__ float fast_tanh(float x) {
  float e = __builtin_amdgcn_exp2f(x * -2.88539008177792681472f);
  return 2.0f * __builtin_amdgcn_rcpf(1.0f + e) - 1.0f;
}

// ---------------- small prep kernels ----------------
__global__ void zero_buf(uint4* __restrict__ p, int n) {
  int i = blockIdx.x * 256 + threadIdx.x;
  if (i < n) p[i] = uint4{0, 0, 0, 0};
}

__global__ void ctx_mean(const float* __restrict__ c, float* __restrict__ ctx) {
  int b = blockIdx.x;
  for (int d = threadIdx.x; d < D_; d += 256) {
    float s = 0.f;
    #pragma unroll
    for (int n = 0; n < 16; ++n) s += c[((size_t)b * 16 + n) * D_ + d];
    ctx[b * D_ + d] = s * (1.0f / 16.0f);
  }
}

// fp32 h0 (register h_prev init) + tagged 8B chunk seeds.
// hb0t: 4 slots x 8192 u32 (L0 h). Seed slot 0, tag 0 (consumed at e=0).
// hb1t: 2 slots x 8192 u32 (L1 h). Seed slot 1, tag 2 (consumed at e=2).
__global__ void h0_compute(const float* __restrict__ ctx, const float* __restrict__ w,
                           const float* __restrict__ bias, float* __restrict__ h0l,
                           uint32_t* __restrict__ hb0t, uint32_t* __restrict__ hb1t) {
  int o = blockIdx.x * 256 + threadIdx.x;   // 8192 unit-pairs
  int layer = o >> 12, b = (o >> 9) & 7, p = o & 511;
  int row = layer * 1024 + 2 * p;
  float s0 = bias[row], s1 = bias[row + 1];
  const float* cb = ctx + b * D_;
  const float* w0 = w + (size_t)row * D_;
  const float* w1 = w0 + D_;
  for (int d = 0; d < D_; ++d) { s0 += cb[d] * w0[d]; s1 += cb[d] * w1[d]; }
  h0l[layer * 8192 + b * 1024 + 2 * p] = s0;
  h0l[layer * 8192 + b * 1024 + 2 * p + 1] = s1;
  uint32_t vals = ((uint32_t)f2bf(s1) << 16) | (uint32_t)f2bf(s0);
  if (layer == 0) {
    uint32_t* dst = hb0t + ((size_t)b * 512 + p) * 2;      // slot 0
    dst[0] = vals; dst[1] = 0u;
  } else {
    uint32_t* dst = hb1t + 8192 + ((size_t)b * 512 + p) * 2;  // slot 1
    dst[0] = vals; dst[1] = 2u;
  }
}

__global__ void gather_embed(const int* __restrict__ seq, const float* __restrict__ emb,
                             unsigned short* __restrict__ x) {
  int r = blockIdx.x;                       // 0..4095 = b*512+s
  int idx = seq[r];
  float4 v = ((const float4*)(emb + (size_t)idx * H_))[threadIdx.x];
  ushort4 o;
  o.x = f2bf(v.x); o.y = f2bf(v.y); o.z = f2bf(v.z); o.w = f2bf(v.w);
  ((ushort4*)(x + (size_t)r * H_))[threadIdx.x] = o;
}

__global__ void f32_to_bf16(const float* __restrict__ in, unsigned short* __restrict__ outp, long n4) {
  long i = blockIdx.x * (long)blockDim.x + threadIdx.x;
  long stride = (long)gridDim.x * blockDim.x;
  for (; i < n4; i += stride) {
    float4 v = ((const float4*)in)[i];
    ushort4 o;
    o.x = f2bf(v.x); o.y = f2bf(v.y); o.z = f2bf(v.z); o.w = f2bf(v.w);
    ((ushort4*)outp)[i] = o;
  }
}

// ---------------- bf16 MFMA GEMM with global_load_lds staging ----------------
#define GL2LDS(g, l) __builtin_amdgcn_global_load_lds( \
    (const __attribute__((address_space(1))) void*)(g), \
    (__attribute__((address_space(3))) void*)(l), 16, 0, 0)

__global__ __launch_bounds__(256) void gemm_bt_bf16(
    const unsigned short* __restrict__ A, const unsigned short* __restrict__ B,
    float* __restrict__ C, const float* __restrict__ bias,
    int M, int N, int K)
{
  __shared__ __align__(16) unsigned short As[128 * 32];
  __shared__ __align__(16) unsigned short Bs[128 * 32];
  const int tid = threadIdx.x;
  const int l = tid & 63;
  const int w = tid >> 6;
  const int wr = w >> 1, wc = w & 1;
  const long row0 = (long)blockIdx.y * 128;
  const long col0 = (long)blockIdx.x * 128;

  f32x4_t acc[4][4];
  #pragma unroll
  for (int m = 0; m < 4; ++m)
    #pragma unroll
    for (int n = 0; n < 4; ++n) acc[m][n] = (f32x4_t)0.0f;

  const int sr = tid >> 2;
  const int sc = (tid & 3) << 3;
  // per-lane global srcs (row pattern matches LDS dest = wavebase + lane*16B)
  const unsigned short* ga0 = &A[(row0 + sr) * K + sc];
  const unsigned short* ga1 = &A[(row0 + sr + 64) * K + sc];
  const unsigned short* gb0 = &B[(col0 + sr) * K + sc];
  const unsigned short* gb1 = &B[(col0 + sr + 64) * K + sc];
  unsigned short* lA0 = &As[w * 512];          // wave-uniform LDS bases
  unsigned short* lA1 = &As[2048 + w * 512];
  unsigned short* lB0 = &Bs[w * 512];
  unsigned short* lB1 = &Bs[2048 + w * 512];

  for (int kt = 0; kt < K; kt += 32) {
    __syncthreads();
    GL2LDS(ga0 + kt, lA0);
    GL2LDS(ga1 + kt, lA1);
    GL2LDS(gb0 + kt, lB0);
    GL2LDS(gb1 + kt, lB1);
    asm volatile("s_waitcnt vmcnt(0)" ::: "memory");
    __syncthreads();

    bf16x8_t af[4], bfr[4];
    #pragma unroll
    for (int m = 0; m < 4; ++m)
      af[m] = *(const bf16x8_t*)&As[(wr * 64 + m * 16 + (l & 15)) * 32 + (l >> 4) * 8];
    #pragma unroll
    for (int n = 0; n < 4; ++n)
      bfr[n] = *(const bf16x8_t*)&Bs[(wc * 64 + n * 16 + (l & 15)) * 32 + (l >> 4) * 8];
    #pragma unroll
    for (int m = 0; m < 4; ++m)
      #pragma unroll
      for (int n = 0; n < 4; ++n)
        acc[m][n] = __builtin_amdgcn_mfma_f32_16x16x32_bf16(af[m], bfr[n], acc[m][n], 0, 0, 0);
  }

  #pragma unroll
  for (int n = 0; n < 4; ++n) {
    const long col = col0 + wc * 64 + n * 16 + (l & 15);
    const float bv = bias[col];
    #pragma unroll
    for (int m = 0; m < 4; ++m) {
      const long rbase = row0 + wr * 64 + m * 16 + ((l >> 4) << 2);
      #pragma unroll
      for (int v = 0; v < 4; ++v)
        C[(rbase + v) * (long)N + col] = acc[m][n][v] + bv;
    }
  }
}

// ---------------- fused 2-layer persistent GRU (spec-tagged + flag confirm) ----------------
// 192 blocks x 256 threads. blk<64: L0, 16 units (j0=blk*16). blk>=64: L1, 8 units.
// Skew-2: epoch e runs L0 @ t=e, L1 @ t=e-2 (514 epochs).
// h chunks: [2xbf16 | tag]; tag = producer_epoch+1. Flags fl[i]=completed+1.
__device__ __forceinline__ void load_wfrag3(const float* __restrict__ W, int j0, int w,
                                            int l15, int lhi, bf16x8_t wf[3][8]) {
  #pragma unroll
  for (int m = 0; m < 3; ++m) {
    const float* pr = W + (size_t)((m << 10) + j0 + l15) * 1024 + (w << 8) + (lhi << 3);
    #pragma unroll
    for (int c = 0; c < 8; ++c) {
      f32x4_t v0 = *(const f32x4_t*)(pr + (c << 5));
      f32x4_t v1 = *(const f32x4_t*)(pr + (c << 5) + 4);
      bf16x8_t f;
      f[0] = (__bf16)v0[0]; f[1] = (__bf16)v0[1]; f[2] = (__bf16)v0[2]; f[3] = (__bf16)v0[3];
      f[4] = (__bf16)v1[0]; f[5] = (__bf16)v1[1]; f[6] = (__bf16)v1[2]; f[7] = (__bf16)v1[3];
      wf[m][c] = f;
    }
  }
}
__device__ __forceinline__ void load_wfrag2(const float* __restrict__ W, int j0, int w,
                                            int l15, int lhi, bf16x8_t wf[2][8]) {
  #pragma unroll
  for (int m = 0; m < 2; ++m) {
    const int idx = m * 16 + l15;           // row within the 24
    const int gg = idx >> 3, uu = idx & 7;
    #pragma unroll
    for (int c = 0; c < 8; ++c) {
      f32x4_t v0 = {0.f,0.f,0.f,0.f}, v1 = {0.f,0.f,0.f,0.f};
      if (idx < 24) {
        const float* p = W + (size_t)((gg << 10) + j0 + uu) * 1024
                           + (w << 8) + (c << 5) + (lhi << 3);
        v0 = *(const f32x4_t*)p;
        v1 = *(const f32x4_t*)(p + 4);
      }
      bf16x8_t f;
      f[0] = (__bf16)v0[0]; f[1] = (__bf16)v0[1]; f[2] = (__bf16)v0[2]; f[3] = (__bf16)v0[3];
      f[4] = (__bf16)v1[0]; f[5] = (__bf16)v1[1]; f[6] = (__bf16)v1[2]; f[7] = (__bf16)v1[3];
      wf[m][c] = f;
    }
  }
}

__device__ __forceinline__ bf16x8_t pack_frag(const uint4 a, const uint4 b) {
  uint4 r; r.x = a.x; r.y = a.z; r.z = b.x; r.w = b.z;
  return __builtin_bit_cast(bf16x8_t, r);
}

__device__ __forceinline__ void issue8(const uint32_t* base, bool realrow,
                                       uint4 (&q0)[8], uint4 (&q1)[8]) {
  if (realrow) {
    #pragma unroll
    for (int c = 0; c < 8; ++c)
      asm volatile("global_load_dwordx4 %0, %2, off offset:%3 sc0 sc1\n\t"
                   "global_load_dwordx4 %1, %2, off offset:%4 sc0 sc1"
                   : "=&v"(q0[c]), "=&v"(q1[c])
                   : "v"(base), "i"(c * 128), "i"(c * 128 + 16) : "memory");
  }
}
// validate already-issued loads; 1 immediate re-spec; then flag-gated reloads.
__device__ __forceinline__ void finish8(const uint32_t* base, uint32_t tag,
                                        const int* flagp, int thr, bool realrow,
                                        uint4 (&q0)[8], uint4 (&q1)[8]) {
  int round = 0;
  for (;;) {
    asm volatile("s_waitcnt vmcnt(0)" ::: "memory");
    __builtin_amdgcn_sched_barrier(0);
    uint32_t bad = 0;
    if (realrow) {
      #pragma unroll
      for (int c = 0; c < 8; ++c)
        bad |= (q0[c].y ^ tag) | (q0[c].w ^ tag) | (q1[c].y ^ tag) | (q1[c].w ^ tag);
    }
    if (!__any(bad != 0)) return;
    if (++round >= 2) {
      while (__hip_atomic_load(flagp, __ATOMIC_RELAXED, __HIP_MEMORY_SCOPE_AGENT) < thr)
        __builtin_amdgcn_s_sleep(1);
    }
    issue8(base, realrow, q0, q1);
  }
}

__global__ __launch_bounds__(256, 1) void gru_fused(
    const float* __restrict__ xg,       // [8,512,3072] L0 input gates (incl b_ih0)
    const float* __restrict__ w_hh,     // [2,3072,1024]
    const float* __restrict__ w_ih,     // [2,3072,1024]
    const float* __restrict__ b_hh,     // [2,3072]
    const float* __restrict__ b_ih,     // [2,3072]
    const float* __restrict__ h0f,      // [2,8,1024]
    unsigned short* __restrict__ y,     // [8,512,1024] final output bf16
    uint32_t* __restrict__ hb0t,        // [4 slots][8][512] tagged chunks (L0 h)
    uint32_t* __restrict__ hb1t,        // [2 slots][8][512] tagged chunks (L1 h)
    int* __restrict__ fl)               // [192*32]: 0..63 L0, 64..191 L1
{
  __shared__ __align__(16) float red[4 * 3 * 256];   // 12KB [wave][slot][16x16]
  const int tid = threadIdx.x;
  const int blk = blockIdx.x;
  const int layer = (blk >= 64);
  const int j0 = layer ? ((blk - 64) * 8) : (blk * 16);
  const int w = tid >> 6;
  const int l = tid & 63;
  const int l15 = l & 15;
  const int lhi = l >> 4;
  const bool realrow = (l15 < 8);

  // ---- weights in registers ----
  bf16x8_t wfh3[3][8];                       // L0 only
  bf16x8_t wfh2[2][8], wfi2[2][8];           // L1 only
  if (layer == 0) {
    load_wfrag3(w_hh, j0, w, l15, lhi, wfh3);
    #pragma unroll
    for (int m = 0; m < 2; ++m)
      #pragma unroll
      for (int c = 0; c < 8; ++c) { wfh2[m][c] = (bf16x8_t)(__bf16)0.0f; wfi2[m][c] = (bf16x8_t)(__bf16)0.0f; }
  } else {
    load_wfrag2(w_hh + (size_t)G3H * H_, j0, w, l15, lhi, wfh2);
    load_wfrag2(w_ih + (size_t)G3H * H_, j0, w, l15, lhi, wfi2);
    #pragma unroll
    for (int m = 0; m < 3; ++m)
      #pragma unroll
      for (int c = 0; c < 8; ++c) wfh3[m][c] = (bf16x8_t)(__bf16)0.0f;
  }

  // ---- gate-thread state ----
  // L0: tid<64, up=tid&7 (units 2up,2up+1), bb=tid>>3.
  // L1: tid<32, up=tid&3, bb=tid>>2.
  const int upL = layer ? (tid & 3) : (tid & 7);
  const int bbL = layer ? (tid >> 2) : (tid >> 3);
  const bool gateth = layer ? (tid < 32) : (tid < 64);
  float gbr0=0.f,gbz0=0.f,gbnh0=0.f,gbni0=0.f,hp0=0.f;
  float gbr1=0.f,gbz1=0.f,gbnh1=0.f,gbni1=0.f,hp1=0.f;
  const float* xgp = nullptr;
  if (gateth) {
    const float* bhh_l = b_hh + (size_t)layer * G3H;
    const float* bih_l = b_ih + (size_t)layer * G3H;
    const int uj = j0 + 2 * upL;
    float bhr0 = bhh_l[uj],     bhz0 = bhh_l[1024 + uj],     bhn0 = bhh_l[2048 + uj];
    float bhr1 = bhh_l[uj + 1], bhz1 = bhh_l[1024 + uj + 1], bhn1 = bhh_l[2048 + uj + 1];
    if (layer == 0) {
      gbr0 = bhr0; gbz0 = bhz0; gbnh0 = bhn0;
      gbr1 = bhr1; gbz1 = bhz1; gbnh1 = bhn1;
      xgp = xg + (size_t)(bbL * S_) * G3H + uj;
    } else {
      gbr0 = bhr0 + bih_l[uj];     gbz0 = bhz0 + bih_l[1024 + uj];
      gbnh0 = bhn0;                gbni0 = bih_l[2048 + uj];
      gbr1 = bhr1 + bih_l[uj + 1]; gbz1 = bhz1 + bih_l[1024 + uj + 1];
      gbnh1 = bhn1;                gbni1 = bih_l[2048 + uj + 1];
    }
    float2 h2 = *(const float2*)&h0f[(size_t)layer * 8192 + bbL * 1024 + uj];
    hp0 = h2.x; hp1 = h2.y;
  }

  const int lane_off = (l15 * 512 + w * 128 + lhi * 4) * 2;   // u32 chunk offset in slot
  // per-lane flag pointers for loader fallback
  const int* flp_h0 = fl + (w * 16 + (l & 15)) * 32;          // L0 producers slice
  const int* flp_h1 = fl + (64 + w * 32 + (l & 31)) * 32;     // L1 producers slice
  // L0 WAR ride-along (wave 0 lanes): 2 L1 flags each
  const int* flp_wa = fl + (64 + 2 * tid) * 32;
  const int* flp_wb = fl + (64 + 2 * tid + 1) * 32;

  for (int e = 0; e <= S_ + 1; ++e) {
    const bool act = layer ? (e >= 2) : (e < S_);
    const int t = layer ? (e - 2) : e;

    uint4 q0[8], q1[8];
    #pragma unroll
    for (int c = 0; c < 8; ++c) { q0[c] = uint4{0,0,0,0}; q1[c] = uint4{0,0,0,0}; }
    float2 xr2 = {0.f,0.f}, xz2 = {0.f,0.f}, xn2 = {0.f,0.f};
    int wa = 0x7fffffff, wb = 0x7fffffff;

    // ---- loop top: speculative issues (before sync A; overlaps producer tail) ----
    const uint32_t* baseA = nullptr;
    if (act) {
      if (layer == 0) {
        baseA = hb0t + (size_t)(e & 3) * 8192 + lane_off;            // h0_e, tag e
        issue8(baseA, realrow, q0, q1);
        if (tid < 64)
          asm volatile("global_load_dword %0, %2, off sc0 sc1\n\t"
                       "global_load_dword %1, %3, off sc0 sc1"
                       : "=&v"(wa), "=&v"(wb) : "v"(flp_wa), "v"(flp_wb) : "memory");
        if (gateth) {
          const float* xp = xgp + (size_t)t * G3H;
          xr2 = *(const float2*)xp;
          xz2 = *(const float2*)(xp + 1024);
          xn2 = *(const float2*)(xp + 2048);
        }
      } else {
        baseA = hb0t + (size_t)((e - 1) & 3) * 8192 + lane_off;      // y0: h0_{e-1}, tag e-1
        issue8(baseA, realrow, q0, q1);
      }
    }
    __syncthreads();   // (A) epoch join; red[e-1] reads complete block-wide

    f32x4_t a0 = (f32x4_t)0.0f, a1 = (f32x4_t)0.0f, a2 = (f32x4_t)0.0f;
    if (act) {
      if (layer == 0) {
        finish8(baseA, (uint32_t)e, flp_h0, e, realrow, q0, q1);
        #pragma unroll
        for (int c = 0; c < 8; ++c) {
          bf16x8_t hf = pack_frag(q0[c], q1[c]);
          a0 = __builtin_amdgcn_mfma_f32_16x16x32_bf16(wfh3[0][c], hf, a0, 0, 0, 0);
          a1 = __builtin_amdgcn_mfma_f32_16x16x32_bf16(wfh3[1][c], hf, a1, 0, 0, 0);
          a2 = __builtin_amdgcn_mfma_f32_16x16x32_bf16(wfh3[2][c], hf, a2, 0, 0, 0);
        }
      } else {
        finish8(baseA, (uint32_t)(e - 1), flp_h0, e - 1, realrow, q0, q1);
        #pragma unroll
        for (int c = 0; c < 8; ++c) {    // ih: r,z into a0; n into a2
          bf16x8_t yf = pack_frag(q0[c], q1[c]);
          a0 = __builtin_amdgcn_mfma_f32_16x16x32_bf16(wfi2[0][c], yf, a0, 0, 0, 0);
          a2 = __builtin_amdgcn_mfma_f32_16x16x32_bf16(wfi2[1][c], yf, a2, 0, 0, 0);
        }
        const uint32_t* baseH = hb1t + (size_t)((e + 1) & 1) * 8192 + lane_off;  // h1, tag e
        issue8(baseH, realrow, q0, q1);
        finish8(baseH, (uint32_t)e, flp_h1, e, realrow, q0, q1);
        #pragma unroll
        for (int c = 0; c < 8; ++c) {    // hh: r,z into a0; n into a1
          bf16x8_t hf = pack_frag(q0[c], q1[c]);
          a0 = __builtin_amdgcn_mfma_f32_16x16x32_bf16(wfh2[0][c], hf, a0, 0, 0, 0);
          a1 = __builtin_amdgcn_mfma_f32_16x16x32_bf16(wfh2[1][c], hf, a1, 0, 0, 0);
        }
      }
      float* rp = red + (w * 3) * 256 + (l << 2);
      *(f32x4_t*)(rp)       = a0;   // L0: R tile | L1: r,z (ih+hh)
      *(f32x4_t*)(rp + 256) = a1;   // L0: Z tile | L1: n hh
      *(f32x4_t*)(rp + 512) = a2;   // L0: Nh     | L1: n ih
    }
    __syncthreads();   // (B) red ready

    if (act && gateth) {
      const int u0 = 2 * upL, u1 = u0 + 1;
      const int i0 = ((((u0 >> 2) << 4) | bbL) << 2) + (u0 & 3);
      const int i1 = ((((u1 >> 2) << 4) | bbL) << 2) + (u1 & 3);
      float r0, z0, n0, r1, z1, n1;
      if (layer == 0) {
        float aR0=0.f,aZ0=0.f,aNh0=0.f,aR1=0.f,aZ1=0.f,aNh1=0.f;
        #pragma unroll
        for (int ww = 0; ww < 4; ++ww) {
          const float* rw = red + ww * 768;
          aR0  += rw[i0];        aR1  += rw[i1];
          aZ0  += rw[256 + i0];  aZ1  += rw[256 + i1];
          aNh0 += rw[512 + i0];  aNh1 += rw[512 + i1];
        }
        r0 = fast_sigmoid(xr2.x + gbr0 + aR0);
        z0 = fast_sigmoid(xz2.x + gbz0 + aZ0);
        n0 = fast_tanh(xn2.x + r0 * (aNh0 + gbnh0));
        r1 = fast_sigmoid(xr2.y + gbr1 + aR1);
        z1 = fast_sigmoid(xz2.y + gbz1 + aZ1);
        n1 = fast_tanh(xn2.y + r1 * (aNh1 + gbnh1));
      } else {
        float aR0=0.f,aZ0=0.f,aNh0=0.f,aNi0=0.f,aR1=0.f,aZ1=0.f,aNh1=0.f,aNi1=0.f;
        #pragma unroll
        for (int ww = 0; ww < 4; ++ww) {
          const float* rw = red + ww * 768;
          aR0  += rw[i0];        aR1  += rw[i1];
          aZ0  += rw[128 + i0];  aZ1  += rw[128 + i1];
          aNh0 += rw[256 + i0];  aNh1 += rw[256 + i1];
          aNi0 += rw[512 + i0];  aNi1 += rw[512 + i1];
        }
        r0 = fast_sigmoid(aR0 + gbr0);
        z0 = fast_sigmoid(aZ0 + gbz0);
        n0 = fast_tanh(aNi0 + gbni0 + r0 * (aNh0 + gbnh0));
        r1 = fast_sigmoid(aR1 + gbr1);
        z1 = fast_sigmoid(aZ1 + gbz1);
        n1 = fast_tanh(aNi1 + gbni1 + r1 * (aNh1 + gbnh1));
      }
      hp0 = (1.0f - z0) * n0 + z0 * hp0;
      hp1 = (1.0f - z1) * n1 + z1 * hp1;
      uint32_t vals = ((uint32_t)f2bf(hp1) << 16) | (uint32_t)f2bf(hp0);
      unsigned long long chunk = ((unsigned long long)(uint32_t)(e + 1) << 32) | vals;
      if (layer == 0) {
        // WAR: all L1 must have completed epoch e-2 before slot (e+1)&3 reuse
        if (e >= 2) {
          while (wa < e - 1) { __builtin_amdgcn_s_sleep(1);
            wa = __hip_atomic_load(flp_wa, __ATOMIC_RELAXED, __HIP_MEMORY_SCOPE_AGENT); }
          while (wb < e - 1) { __builtin_amdgcn_s_sleep(1);
            wb = __hip_atomic_load(flp_wb, __ATOMIC_RELAXED, __HIP_MEMORY_SCOPE_AGENT); }
        }
        uint32_t* hdst = hb0t + (size_t)((e + 1) & 3) * 8192
                              + ((size_t)bbL * 512 + (j0 >> 1) + upL) * 2;
        asm volatile("global_store_dwordx2 %0, %1, off sc0 sc1"
                     :: "v"(hdst), "v"(chunk) : "memory");
      } else {
        uint32_t* hdst = hb1t + (size_t)(e & 1) * 8192
                              + ((size_t)bbL * 512 + (j0 >> 1) + upL) * 2;
        *(uint32_t*)&y[(((size_t)(bbL * S_ + t)) << 10) + j0 + 2 * upL] = vals;
        asm volatile("global_store_dwordx2 %0, %1, off sc0 sc1"
                     :: "v"(hdst), "v"(chunk) : "memory");
      }
    }
    asm volatile("s_waitcnt vmcnt(0)" ::: "memory");   // drain gate-wave stores
    if (tid == 0)
      __hip_atomic_store(&fl[blk * 32], e + 1,
                         __ATOMIC_RELAXED, __HIP_MEMORY_SCOPE_AGENT);
  }
}

// ---------------- launch ----------------
extern "C" void kernel_launch(void* const* d_in, const int* in_sizes, int n_in,
                              void* d_out, int out_size, void* d_ws, size_t ws_size,
                              hipStream_t stream) {
  (void)in_sizes; (void)n_in; (void)out_size; (void)ws_size;
  const float* concepts = (const float*)d_in[0];
  const int*   seq      = (const int*)d_in[1];
  const float* emb      = (const float*)d_in[2];
  const float* w_ih     = (const float*)d_in[3];
  const float* w_hh     = (const float*)d_in[4];
  const float* b_ih     = (const float*)d_in[5];
  const float* b_hh     = (const float*)d_in[6];
  const float* fc_w     = (const float*)d_in[7];
  const float* fc_b     = (const float*)d_in[8];
  const float* c2h_w    = (const float*)d_in[9];
  const float* c2h_b    = (const float*)d_in[10];
  float* out = (float*)d_out;

  char* ws = (char*)d_ws;
  size_t off = 0;
  auto alloc = [&](size_t bytes) {
    char* p = ws + off;
    off += (bytes + 255) & ~(size_t)255;
    return p;
  };
  unsigned short* xy   = (unsigned short*)alloc((size_t)B_ * S_ * H_ * 2);   // x bf16, then y
  float*          xg   = (float*)alloc((size_t)B_ * S_ * G3H * 4);           // L0 input gates
  unsigned short* wihb = (unsigned short*)alloc((size_t)G3H * H_ * 2);       // L0 W_ih bf16
  unsigned short* fcwb = (unsigned short*)alloc((size_t)V_ * H_ * 2);
  float*          ctx  = (float*)alloc((size_t)B_ * D_ * 4);
  float*          h0l  = (float*)alloc((size_t)2 * B_ * H_ * 4);
  uint32_t*       hb0t = (uint32_t*)alloc((size_t)4 * 8192 * 4);             // 128KB
  uint32_t*       hb1t = (uint32_t*)alloc((size_t)2 * 8192 * 4);             // 64KB
  int*            fl   = (int*)alloc((size_t)192 * 32 * 4);                  // 24KB

  // flags MUST be zeroed every launch (monotone counters within a launch)
  zero_buf<<<dim3(6), dim3(256), 0, stream>>>((uint4*)fl, 192 * 32 / 4);
  ctx_mean<<<dim3(8), dim3(256), 0, stream>>>(concepts, ctx);
  h0_compute<<<dim3(32), dim3(256), 0, stream>>>(ctx, c2h_w, c2h_b, h0l, hb0t, hb1t);
  gather_embed<<<dim3(B_ * S_), dim3(256), 0, stream>>>(seq, emb, xy);
  f32_to_bf16<<<dim3(1024), dim3(256), 0, stream>>>(w_ih, wihb, (long)G3H * H_ / 4);
  f32_to_bf16<<<dim3(2048), dim3(256), 0, stream>>>(fc_w, fcwb, (long)V_ * H_ / 4);

  // L0 input gates (GEMM)
  gemm_bt_bf16<<<dim3(G3H / 128, (B_ * S_) / 128), dim3(256), 0, stream>>>(
      xy, wihb, xg, b_ih, B_ * S_, G3H, H_);

  // fused 2-layer skew-2 recurrence
  gru_fused<<<dim3(192), dim3(256), 0, stream>>>(
      xg, w_hh, w_ih, b_hh, b_ih, h0l, xy, hb0t, hb1t, fl);

  // logits
  gemm_bt_bf16<<<dim3(V_ / 128, (B_ * S_) / 128), dim3(256), 0, stream>>>(
      xy, fcwb, out, fc_b, B_ * S_, V_, H_);
}

// Round 10
// 2297.180 us; speedup vs baseline: 2.1316x; 1.7442x over previous
//
#include <hip/hip_runtime.h>
#include <hip/hip_bf16.h>
#include <stdint.h>

#define B_ 8
#define S_ 512
#define H_ 1024
#define V_ 32000
#define D_ 768
#define G3H (3*H_)
#define FSTR 32   // flag stride (ints)

typedef __bf16 bf16x8_t __attribute__((ext_vector_type(8)));
typedef float f32x4_t __attribute__((ext_vector_type(4)));

__device__ __forceinline__ unsigned short f2bf(float f) {
  unsigned int u = __float_as_uint(f);
  u += 0x7fffu + ((u >> 16) & 1u);      // RNE
  return (unsigned short)(u >> 16);
}
__device__ __forceinline__ float fast_sigmoid(float x) {
  float e = __builtin_amdgcn_exp2f(x * -1.44269504088896340736f);
  return __builtin_amdgcn_rcpf(1.0f + e);
}
__device__ __forceinline__ float fast_tanh(float x) {
  float e = __builtin_amdgcn_exp2f(x * -2.88539008177792681472f);
  return 2.0f * __builtin_amdgcn_rcpf(1.0f + e) - 1.0f;
}

// ---------------- small prep kernels ----------------
__global__ void zero_buf(uint4* __restrict__ p, int n) {
  int i = blockIdx.x * 256 + threadIdx.x;
  if (i < n) p[i] = uint4{0, 0, 0, 0};
}

__global__ void ctx_mean(const float* __restrict__ c, float* __restrict__ ctx) {
  int b = blockIdx.x;
  for (int d = threadIdx.x; d < D_; d += 256) {
    float s = 0.f;
    #pragma unroll
    for (int n = 0; n < 16; ++n) s += c[((size_t)b * 16 + n) * D_ + d];
    ctx[b * D_ + d] = s * (1.0f / 16.0f);
  }
}

// fp32 h0 (register h_prev init) + bf16 seeds: hb0 slot 0 (L0), hb1 slot 1 (L1).
__global__ void h0_compute(const float* __restrict__ ctx, const float* __restrict__ w,
                           const float* __restrict__ bias, float* __restrict__ h0l,
                           uint32_t* __restrict__ hb0, uint32_t* __restrict__ hb1) {
  int o = blockIdx.x * 256 + threadIdx.x;   // 8192 unit-pairs
  int layer = o >> 12, b = (o >> 9) & 7, p = o & 511;
  int row = layer * 1024 + 2 * p;
  float s0 = bias[row], s1 = bias[row + 1];
  const float* cb = ctx + b * D_;
  const float* w0 = w + (size_t)row * D_;
  const float* w1 = w0 + D_;
  for (int d = 0; d < D_; ++d) { s0 += cb[d] * w0[d]; s1 += cb[d] * w1[d]; }
  h0l[layer * 8192 + b * 1024 + 2 * p] = s0;
  h0l[layer * 8192 + b * 1024 + 2 * p + 1] = s1;
  uint32_t vals = ((uint32_t)f2bf(s1) << 16) | (uint32_t)f2bf(s0);
  if (layer == 0) hb0[(size_t)b * 512 + p] = vals;            // slot 0
  else            hb1[4096 + (size_t)b * 512 + p] = vals;     // slot 1
}

__global__ void gather_embed(const int* __restrict__ seq, const float* __restrict__ emb,
                             unsigned short* __restrict__ x) {
  int r = blockIdx.x;                       // 0..4095 = b*512+s
  int idx = seq[r];
  float4 v = ((const float4*)(emb + (size_t)idx * H_))[threadIdx.x];
  ushort4 o;
  o.x = f2bf(v.x); o.y = f2bf(v.y); o.z = f2bf(v.z); o.w = f2bf(v.w);
  ((ushort4*)(x + (size_t)r * H_))[threadIdx.x] = o;
}

__global__ void f32_to_bf16(const float* __restrict__ in, unsigned short* __restrict__ outp, long n4) {
  long i = blockIdx.x * (long)blockDim.x + threadIdx.x;
  long stride = (long)gridDim.x * blockDim.x;
  for (; i < n4; i += stride) {
    float4 v = ((const float4*)in)[i];
    ushort4 o;
    o.x = f2bf(v.x); o.y = f2bf(v.y); o.z = f2bf(v.z); o.w = f2bf(v.w);
    ((ushort4*)outp)[i] = o;
  }
}

// ---------------- bf16 MFMA GEMM with global_load_lds staging ----------------
#define GL2LDS(g, l) __builtin_amdgcn_global_load_lds( \
    (const __attribute__((address_space(1))) void*)(g), \
    (__attribute__((address_space(3))) void*)(l), 16, 0, 0)

__global__ __launch_bounds__(256) void gemm_bt_bf16(
    const unsigned short* __restrict__ A, const unsigned short* __restrict__ B,
    float* __restrict__ C, const float* __restrict__ bias,
    int M, int N, int K)
{
  __shared__ __align__(16) unsigned short As[128 * 32];
  __shared__ __align__(16) unsigned short Bs[128 * 32];
  const int tid = threadIdx.x;
  const int l = tid & 63;
  const int w = tid >> 6;
  const int wr = w >> 1, wc = w & 1;
  const long row0 = (long)blockIdx.y * 128;
  const long col0 = (long)blockIdx.x * 128;

  f32x4_t acc[4][4];
  #pragma unroll
  for (int m = 0; m < 4; ++m)
    #pragma unroll
    for (int n = 0; n < 4; ++n) acc[m][n] = (f32x4_t)0.0f;

  const int sr = tid >> 2;
  const int sc = (tid & 3) << 3;
  const unsigned short* ga0 = &A[(row0 + sr) * K + sc];
  const unsigned short* ga1 = &A[(row0 + sr + 64) * K + sc];
  const unsigned short* gb0 = &B[(col0 + sr) * K + sc];
  const unsigned short* gb1 = &B[(col0 + sr + 64) * K + sc];
  unsigned short* lA0 = &As[w * 512];
  unsigned short* lA1 = &As[2048 + w * 512];
  unsigned short* lB0 = &Bs[w * 512];
  unsigned short* lB1 = &Bs[2048 + w * 512];

  for (int kt = 0; kt < K; kt += 32) {
    __syncthreads();
    GL2LDS(ga0 + kt, lA0);
    GL2LDS(ga1 + kt, lA1);
    GL2LDS(gb0 + kt, lB0);
    GL2LDS(gb1 + kt, lB1);
    asm volatile("s_waitcnt vmcnt(0)" ::: "memory");
    __syncthreads();

    bf16x8_t af[4], bfr[4];
    #pragma unroll
    for (int m = 0; m < 4; ++m)
      af[m] = *(const bf16x8_t*)&As[(wr * 64 + m * 16 + (l & 15)) * 32 + (l >> 4) * 8];
    #pragma unroll
    for (int n = 0; n < 4; ++n)
      bfr[n] = *(const bf16x8_t*)&Bs[(wc * 64 + n * 16 + (l & 15)) * 32 + (l >> 4) * 8];
    #pragma unroll
    for (int m = 0; m < 4; ++m)
      #pragma unroll
      for (int n = 0; n < 4; ++n)
        acc[m][n] = __builtin_amdgcn_mfma_f32_16x16x32_bf16(af[m], bfr[n], acc[m][n], 0, 0, 0);
  }

  #pragma unroll
  for (int n = 0; n < 4; ++n) {
    const long col = col0 + wc * 64 + n * 16 + (l & 15);
    const float bv = bias[col];
    #pragma unroll
    for (int m = 0; m < 4; ++m) {
      const long rbase = row0 + wr * 64 + m * 16 + ((l >> 4) << 2);
      #pragma unroll
      for (int v = 0; v < 4; ++v)
        C[(rbase + v) * (long)N + col] = acc[m][n][v] + bv;
    }
  }
}

// ---------------- 3-stage skewed GRU pipeline ----------------
// 192 blocks x 128 threads (2 waves). stage = blk>>6: 0=L0 rec, 1=mid ih, 2=L1 rec.
// g = blk&63, units/rows j0 = g*16 (48 W-rows = 3 gate tiles). K halves per wave.
// Epoch e: stage0 t=e, stage1 t=e-1 (xg1 = W_ih1*y0+b_ih1), stage2 t=e-2.
// Sync: R7-proven per-block flags fl[stage*64+g] = completed epoch + 1.
//   stage0 waits: fl0>=e (sibling h0), flm>=e-2 (WAR on hb0 slot rotation)
//   stage1 waits: fl0>=e (y0 data),    fl2>=e-2 (WAR on xg1 slot rotation)
//   stage2 waits: flm>=e (xg1 data),   fl2>=e   (sibling h1 + WAR)
__global__ __launch_bounds__(128, 1) void gru_pipe(
    const float* __restrict__ xg,       // [8,512,3072] L0 input gates (incl b_ih0)
    const float* __restrict__ w_hh,     // [2,3072,1024]
    const float* __restrict__ w_ih,     // [2,3072,1024]
    const float* __restrict__ b_hh,     // [2,3072]
    const float* __restrict__ b_ih,     // [2,3072]
    const float* __restrict__ h0f,      // [2,8,1024]
    unsigned short* __restrict__ y,     // [8,512,1024] final output bf16
    unsigned short* __restrict__ hb0,   // [4 slots][8][1024] bf16 (L0 h / y0)
    unsigned short* __restrict__ hb1,   // [2 slots][8][1024] bf16 (L1 h)
    float* __restrict__ xg1,            // [4 slots][3][8][1024] f32
    int* __restrict__ fl)               // [192*FSTR]
{
  __shared__ __align__(16) float red[3 * 256];   // 3KB: wave-1 partials
  const int tid = threadIdx.x;
  const int blk = blockIdx.x;
  const int stage = blk >> 6;
  const int g = blk & 63;
  const int j0 = g << 4;
  const int w = tid >> 6;
  const int l = tid & 63;
  const int hi = l >> 4;
  const int l15 = l & 15;
  const bool realcol = (l15 < 8);
  const bool gate = (w == 0) && realcol;

  // ---- weights: 3 tiles x 16 chunks (this wave's K-half) in registers ----
  const float* W = (stage == 0) ? w_hh
                 : (stage == 1) ? (w_ih + (size_t)G3H * H_)
                                : (w_hh + (size_t)G3H * H_);
  bf16x8_t wf[3][16];
  #pragma unroll
  for (int m = 0; m < 3; ++m) {
    const float* pr = W + (size_t)((m << 10) + j0 + l15) * 1024 + (w << 9) + (hi << 3);
    #pragma unroll
    for (int c = 0; c < 16; ++c) {
      f32x4_t v0 = *(const f32x4_t*)(pr + (c << 5));
      f32x4_t v1 = *(const f32x4_t*)(pr + (c << 5) + 4);
      bf16x8_t f;
      f[0]=(__bf16)v0[0]; f[1]=(__bf16)v0[1]; f[2]=(__bf16)v0[2]; f[3]=(__bf16)v0[3];
      f[4]=(__bf16)v1[0]; f[5]=(__bf16)v1[1]; f[6]=(__bf16)v1[2]; f[7]=(__bf16)v1[3];
      wf[m][c] = f;
    }
  }

  // ---- gate-lane constants (rows 4hi..4hi+3, batch l15) ----
  f32x4_t bR = (f32x4_t)0.f, bZ = (f32x4_t)0.f, bN = (f32x4_t)0.f, hp = (f32x4_t)0.f;
  if (gate) {
    const int co = j0 + (hi << 2);
    if (stage == 1) {
      const float* bi = b_ih + G3H;
      bR = *(const f32x4_t*)(bi + co);
      bZ = *(const f32x4_t*)(bi + 1024 + co);
      bN = *(const f32x4_t*)(bi + 2048 + co);
    } else {
      const float* bh = b_hh + (stage == 2 ? G3H : 0);
      bR = *(const f32x4_t*)(bh + co);
      bZ = *(const f32x4_t*)(bh + 1024 + co);
      bN = *(const f32x4_t*)(bh + 2048 + co);
      hp = *(const f32x4_t*)(h0f + (stage == 2 ? 8192 : 0) + l15 * 1024 + co);
    }
  }

  // ---- poll assignment: 128 threads, 1 flag each ----
  const int* pollp;
  int thrOff;
  if (stage == 0)      { pollp = fl + ((w == 0 ? l : 64 + l) * FSTR);  thrOff = (w == 0) ? 0 : -2; }
  else if (stage == 1) { pollp = fl + ((w == 0 ? l : 128 + l) * FSTR); thrOff = (w == 0) ? 0 : -2; }
  else                 { pollp = fl + ((w == 0 ? 64 + l : 128 + l) * FSTR); thrOff = 0; }
  int* const myfl = fl + (stage * 64 + g) * FSTR;

  const int frag_off = l15 * 1024 + (w << 9) + (hi << 3);   // u16 offset in a slot

  for (int e = 0; e <= S_ + 1; ++e) {
    const int t = e - stage;
    const bool act = (t >= 0) && (t < S_);

    // early xg loads for stage 0 (static data, off the sync path)
    f32x4_t xR = (f32x4_t)0.f, xZ = (f32x4_t)0.f, xN = (f32x4_t)0.f;
    if (stage == 0 && act && gate) {
      const float* xp = xg + (size_t)(l15 * S_ + t) * G3H + j0 + (hi << 2);
      xR = *(const f32x4_t*)xp;
      xZ = *(const f32x4_t*)(xp + 1024);
      xN = *(const f32x4_t*)(xp + 2048);
    }
    // ---- poll (divergent loop; wave reconverges when all lanes satisfied) ----
    {
      const int thr = e + thrOff;
      while (__hip_atomic_load(pollp, __ATOMIC_RELAXED, __HIP_MEMORY_SCOPE_AGENT) < thr)
        __builtin_amdgcn_s_sleep(1);
    }
    __syncthreads();   // S1: poll done block-wide; also protects red across epochs

    f32x4_t a0 = (f32x4_t)0.f, a1 = (f32x4_t)0.f, a2 = (f32x4_t)0.f;
    if (act) {
      const unsigned short* hsrc =
          (stage == 2) ? (hb1 + (size_t)((e + 1) & 1) * 8192)
                       : (hb0 + (size_t)(e & 3) * 8192);
      f32x4_t hv[16];
      #pragma unroll
      for (int c = 0; c < 16; ++c) hv[c] = (f32x4_t)0.f;
      const unsigned short* hpt = hsrc + frag_off;
      if (realcol) {
        #pragma unroll
        for (int c = 0; c < 16; ++c)
          asm volatile("global_load_dwordx4 %0, %1, off offset:%2 sc0 sc1"
                       : "=v"(hv[c]) : "v"(hpt), "i"(c * 64) : "memory");
      }
      if (stage == 2 && gate) {
        const float* xp1 = xg1 + ((size_t)(((e - 2) & 3) * 3) * 8 + l15) * 1024 + j0 + (hi << 2);
        asm volatile("global_load_dwordx4 %0, %1, off sc0 sc1" : "=v"(xR) : "v"(xp1) : "memory");
        asm volatile("global_load_dwordx4 %0, %1, off sc0 sc1" : "=v"(xZ) : "v"(xp1 + 8192) : "memory");
        asm volatile("global_load_dwordx4 %0, %1, off sc0 sc1" : "=v"(xN) : "v"(xp1 + 16384) : "memory");
      }
      asm volatile("s_waitcnt vmcnt(0)" ::: "memory");
      __builtin_amdgcn_sched_barrier(0);
      #pragma unroll
      for (int c = 0; c < 16; ++c) {
        bf16x8_t hf = __builtin_bit_cast(bf16x8_t, hv[c]);
        a0 = __builtin_amdgcn_mfma_f32_16x16x32_bf16(wf[0][c], hf, a0, 0, 0, 0);
        a1 = __builtin_amdgcn_mfma_f32_16x16x32_bf16(wf[1][c], hf, a1, 0, 0, 0);
        a2 = __builtin_amdgcn_mfma_f32_16x16x32_bf16(wf[2][c], hf, a2, 0, 0, 0);
      }
      if (w == 1) {
        *(f32x4_t*)&red[(l << 2)]       = a0;
        *(f32x4_t*)&red[256 + (l << 2)] = a1;
        *(f32x4_t*)&red[512 + (l << 2)] = a2;
      }
    }
    __syncthreads();   // S2: partials ready

    if (act && gate) {
      a0 += *(const f32x4_t*)&red[(l << 2)];
      a1 += *(const f32x4_t*)&red[256 + (l << 2)];
      a2 += *(const f32x4_t*)&red[512 + (l << 2)];
      if (stage == 1) {
        f32x4_t o0 = a0 + bR, o1 = a1 + bZ, o2 = a2 + bN;
        float* dst = xg1 + ((size_t)(((e - 1) & 3) * 3) * 8 + l15) * 1024 + j0 + (hi << 2);
        asm volatile("global_store_dwordx4 %0, %1, off sc0 sc1" :: "v"(dst), "v"(o0) : "memory");
        asm volatile("global_store_dwordx4 %0, %1, off sc0 sc1" :: "v"(dst + 8192), "v"(o1) : "memory");
        asm volatile("global_store_dwordx4 %0, %1, off sc0 sc1" :: "v"(dst + 16384), "v"(o2) : "memory");
      } else {
        #pragma unroll
        for (int r = 0; r < 4; ++r) {
          float rr = fast_sigmoid(xR[r] + a0[r] + bR[r]);
          float zz = fast_sigmoid(xZ[r] + a1[r] + bZ[r]);
          float nn = fast_tanh(xN[r] + rr * (a2[r] + bN[r]));
          hp[r] = (1.0f - zz) * nn + zz * hp[r];
        }
        uint32_t w0 = ((uint32_t)f2bf(hp[1]) << 16) | (uint32_t)f2bf(hp[0]);
        uint32_t w1 = ((uint32_t)f2bf(hp[3]) << 16) | (uint32_t)f2bf(hp[2]);
        unsigned long long chunk = ((unsigned long long)w1 << 32) | w0;
        const int uoff = l15 * 1024 + j0 + (hi << 2);
        unsigned short* hdst = (stage == 0)
            ? (hb0 + (size_t)((e + 1) & 3) * 8192 + uoff)
            : (hb1 + (size_t)(e & 1) * 8192 + uoff);
        if (stage == 2) {
          uint2* yd = (uint2*)&y[((size_t)(l15 * S_ + t) << 10) + j0 + (hi << 2)];
          *yd = uint2{w0, w1};   // normal cached store (logits GEMM reads later)
        }
        asm volatile("global_store_dwordx2 %0, %1, off sc0 sc1"
                     :: "v"(hdst), "v"(chunk) : "memory");
      }
    }
    asm volatile("s_waitcnt vmcnt(0)" ::: "memory");   // drain wave-0 stores
    if (tid == 0)
      __hip_atomic_store(myfl, e + 1, __ATOMIC_RELAXED, __HIP_MEMORY_SCOPE_AGENT);
  }
}

// ---------------- launch ----------------
extern "C" void kernel_launch(void* const* d_in, const int* in_sizes, int n_in,
                              void* d_out, int out_size, void* d_ws, size_t ws_size,
                              hipStream_t stream) {
  (void)in_sizes; (void)n_in; (void)out_size; (void)ws_size;
  const float* concepts = (const float*)d_in[0];
  const int*   seq      = (const int*)d_in[1];
  const float* emb      = (const float*)d_in[2];
  const float* w_ih     = (const float*)d_in[3];
  const float* w_hh     = (const float*)d_in[4];
  const float* b_ih     = (const float*)d_in[5];
  const float* b_hh     = (const float*)d_in[6];
  const float* fc_w     = (const float*)d_in[7];
  const float* fc_b     = (const float*)d_in[8];
  const float* c2h_w    = (const float*)d_in[9];
  const float* c2h_b    = (const float*)d_in[10];
  float* out = (float*)d_out;

  char* ws = (char*)d_ws;
  size_t off = 0;
  auto alloc = [&](size_t bytes) {
    char* p = ws + off;
    off += (bytes + 255) & ~(size_t)255;
    return p;
  };
  unsigned short* xy   = (unsigned short*)alloc((size_t)B_ * S_ * H_ * 2);   // x bf16, then y
  float*          xg   = (float*)alloc((size_t)B_ * S_ * G3H * 4);           // L0 input gates
  unsigned short* wihb = (unsigned short*)alloc((size_t)G3H * H_ * 2);       // L0 W_ih bf16
  unsigned short* fcwb = (unsigned short*)alloc((size_t)V_ * H_ * 2);
  float*          ctx  = (float*)alloc((size_t)B_ * D_ * 4);
  float*          h0l  = (float*)alloc((size_t)2 * B_ * H_ * 4);
  unsigned short* hb0  = (unsigned short*)alloc((size_t)4 * 8192 * 2);       // 64KB
  unsigned short* hb1  = (unsigned short*)alloc((size_t)2 * 8192 * 2);       // 32KB
  float*          xg1  = (float*)alloc((size_t)4 * 3 * 8 * 1024 * 4);        // 384KB
  int*            fl   = (int*)alloc((size_t)192 * FSTR * 4);                // 24KB

  // flags MUST be zeroed every launch (monotone counters within a launch)
  zero_buf<<<dim3(6), dim3(256), 0, stream>>>((uint4*)fl, 192 * FSTR / 4);
  ctx_mean<<<dim3(8), dim3(256), 0, stream>>>(concepts, ctx);
  h0_compute<<<dim3(32), dim3(256), 0, stream>>>(ctx, c2h_w, c2h_b, h0l,
                                                 (uint32_t*)hb0, (uint32_t*)hb1);
  gather_embed<<<dim3(B_ * S_), dim3(256), 0, stream>>>(seq, emb, xy);
  f32_to_bf16<<<dim3(1024), dim3(256), 0, stream>>>(w_ih, wihb, (long)G3H * H_ / 4);
  f32_to_bf16<<<dim3(2048), dim3(256), 0, stream>>>(fc_w, fcwb, (long)V_ * H_ / 4);

  // L0 input gates (GEMM)
  gemm_bt_bf16<<<dim3(G3H / 128, (B_ * S_) / 128), dim3(256), 0, stream>>>(
      xy, wihb, xg, b_ih, B_ * S_, G3H, H_);

  // 3-stage skewed recurrence pipeline
  gru_pipe<<<dim3(192), dim3(128), 0, stream>>>(
      xg, w_hh, w_ih, b_hh, b_ih, h0l, xy, hb0, hb1, xg1, fl);

  // logits
  gemm_bt_bf16<<<dim3(V_ / 128, (B_ * S_) / 128), dim3(256), 0, stream>>>(
      xy, fcwb, out, fc_b, B_ * S_, V_, H_);
}